// Round 1
// 176.623 us; speedup vs baseline: 1.0658x; 1.0658x over previous
//
#include <hip/hip_runtime.h>
#include <hip/hip_bf16.h>
#include <stdint.h>

// B=2, N=2048, D=1024, H=8, DH=128. Inputs fp32, OUTPUT fp32.
// qkv col (reference) = kk*1024 + dd*8 + hh (head innermost). No softmax =>
//   out = sum_h Q_h (K_h^T V_h) Wo_h^T + b_o.
// v2 pipeline (6 kernels):
//   conv_all: x->bf16; w_qkv rows PERMUTED so gemm1 emits cols [kk][hh][dd];
//             w_o->bf16; b_qkv permuted (fp32).
//   gemm1:    qkv[4096][3072] bf16 (+bias), cols grouped per head.
//   kv_part:  Mpart[bh][ch][e][d] += K[n][e]*V[n][d] (fp32, vector ALU),
//             K/V read as strided views of qkv (stride 3072).
//   reduce_m: M[bh][e][d] bf16 = sum_ch Mpart (row-major, no transpose).
//   wprime:   Wt_b[o][h*128+e] = sum_d wo[o][h*128+d]*M[bh][e][d]  (MFMA, K=128)
//   gemm2:    out[bn][o] = sum_he qkv[bn][he] * Wt_b[o][he] + b_o  (fp32 out)
// ws map (40 MB):
//   [0,8M)    xb      -> Mb [0,0.5M) + Wt [1M,5M)   (after gemm1)
//   [8,14M)   wqkvb   (dead after gemm1)
//   [14,16M)  wob     (live through wprime)
//   [16,40M)  qkv     (live through gemm2)
// d_out (16MB): bqp [0,12K) during gemm1; Mpart [0,16M) after gemm1;
//   overwritten by gemm2's final output.

typedef __bf16 bf16_t;
typedef __bf16 bf16x4 __attribute__((ext_vector_type(4)));
typedef __bf16 bf16x8 __attribute__((ext_vector_type(8)));
typedef float  fx4    __attribute__((ext_vector_type(4)));
typedef unsigned short u16;
typedef u16 u16x8 __attribute__((ext_vector_type(8)));

typedef const void __attribute__((address_space(1)))* gas_ptr;
typedef void __attribute__((address_space(3)))*       las_ptr;

__device__ __forceinline__ void gl_lds16(const void* g, void* l) {
  __builtin_amdgcn_global_load_lds((gas_ptr)g, (las_ptr)l, 16, 0, 0);
}

// ---------------------------------------------------------------------------
__global__ __launch_bounds__(256) void beacon_kernel(float* out, float val, int n)
{
  const int i = blockIdx.x * 256 + threadIdx.x;
  if (i < n) out[i] = val;
}

// ---------------------------------------------------------------------------
// All input conversions in one kernel. Tasks:
//   [0, 1048576)        : x float4 -> xb bf16x4
//   [1048576, 1835008)  : w_qkv float4 -> wqkvb, ROW-PERMUTED (c' = kk*1024+hh*128+dd)
//   [1835008, 2097152)  : w_o float4 -> wob
//   [2097152, 2097920)  : b_qkv permuted -> bqp (fp32 gather, 768 float4 tasks)
__global__ __launch_bounds__(256) void conv_all_kernel(
    const float* __restrict__ x, const float* __restrict__ wq,
    const float* __restrict__ wo, const float* __restrict__ bq,
    bf16_t* __restrict__ xb, bf16_t* __restrict__ wqkvb,
    bf16_t* __restrict__ wob, float* __restrict__ bqp)
{
  const int i = blockIdx.x * 256 + threadIdx.x;   // < 2097920
  if (i < 2097152) {
    const float* src; bf16_t* dst; int soff, doff;
    if (i < 1048576) { src = x; dst = xb; soff = i; doff = i; }
    else if (i < 1835008) {
      const int j  = i - 1048576;
      const int rp = j >> 8, g = j & 255;       // dst row c' (0..3071), float4 group
      const int kk = rp >> 10, rem = rp & 1023;
      const int hh = rem >> 7,  dd = rem & 127;
      const int r  = kk * 1024 + dd * 8 + hh;   // src row c
      src = wq; dst = wqkvb; soff = r * 256 + g; doff = j;
    } else {
      const int j = i - 1835008;
      src = wo; dst = wob; soff = j; doff = j;
    }
    const float4 v = ((const float4*)src)[soff];
    bf16x4 o;
    o[0] = (bf16_t)v.x; o[1] = (bf16_t)v.y; o[2] = (bf16_t)v.z; o[3] = (bf16_t)v.w;
    ((bf16x4*)dst)[doff] = o;
  } else if (i < 2097920) {
    const int j = i - 2097152;                  // 0..767
    float4 v;
    float* pv = (float*)&v;
#pragma unroll
    for (int q = 0; q < 4; ++q) {
      const int cp = j * 4 + q;
      const int kk = cp >> 10, rem = cp & 1023;
      const int hh = rem >> 7,  dd = rem & 127;
      pv[q] = bq[kk * 1024 + dd * 8 + hh];
    }
    ((float4*)bqp)[j] = v;
  }
}

// ---------------------------------------------------------------------------
// MFMA GEMM (m97 structure), K=1024: C[M,N] = A[M,1024] @ Bt[N,1024]^T + bias.
// lda/ldb parametrized (strided A views). bt_bstride: Bt element offset added
// for row0 >= 2048 (per-batch B in gemm2).
// mode 0: bf16 out. mode 1: fp32 out.
__global__ __launch_bounds__(256) void mfma_gemm_kernel(
    const bf16_t* __restrict__ A, int lda,
    const bf16_t* __restrict__ Bt0, int ldb, size_t bt_bstride,
    const float* __restrict__ bias,
    bf16_t* __restrict__ outb, float* __restrict__ outf, int ldc, int mode)
{
  __shared__ __align__(16) short As[128*32];
  __shared__ __align__(16) short Bs[128*32];
  const int t    = threadIdx.x;
  const int lane = t & 63;
  const int w    = t >> 6;
  const int wr   = (w >> 1) << 6;
  const int wc   = (w & 1) << 6;
  const int lrow = lane & 15;
  const int kq   = (lane >> 4) << 3;
  const int row0 = blockIdx.y * 128;
  const int col0 = blockIdx.x * 128;
  const bf16_t* Bt = Bt0 + (row0 >= 2048 ? bt_bstride : (size_t)0);

  const int i0 = t, i1 = t + 256;
  const bf16_t* a0 = A  + (size_t)(row0 + (i0 >> 2)) * lda + ((i0 & 3) << 3);
  const bf16_t* a1 = A  + (size_t)(row0 + (i1 >> 2)) * lda + ((i1 & 3) << 3);
  const bf16_t* b0 = Bt + (size_t)(col0 + (i0 >> 2)) * ldb + ((i0 & 3) << 3);
  const bf16_t* b1 = Bt + (size_t)(col0 + (i1 >> 2)) * ldb + ((i1 & 3) << 3);
  short* sa0 = &As[i0 * 8]; short* sa1 = &As[i1 * 8];
  short* sb0 = &Bs[i0 * 8]; short* sb1 = &Bs[i1 * 8];

  fx4 acc[4][4] = {};

  for (int k0 = 0; k0 < 1024; k0 += 32) {
    gl_lds16(a0 + k0, sa0);
    gl_lds16(a1 + k0, sa1);
    gl_lds16(b0 + k0, sb0);
    gl_lds16(b1 + k0, sb1);
    __syncthreads();
    bf16x8 af[4], bfr[4];
#pragma unroll
    for (int i = 0; i < 4; ++i)
      af[i] = *(const bf16x8*)&As[(wr + i*16 + lrow)*32 + kq];
#pragma unroll
    for (int j = 0; j < 4; ++j)
      bfr[j] = *(const bf16x8*)&Bs[(wc + j*16 + lrow)*32 + kq];
#pragma unroll
    for (int i = 0; i < 4; ++i)
#pragma unroll
      for (int j = 0; j < 4; ++j)
        acc[i][j] = __builtin_amdgcn_mfma_f32_16x16x32_bf16(af[i], bfr[j], acc[i][j], 0, 0, 0);
    __syncthreads();
  }

#pragma unroll
  for (int j = 0; j < 4; ++j) {
    const int col = col0 + wc + j*16 + lrow;
    const float bv = bias[col];
#pragma unroll
    for (int i = 0; i < 4; ++i) {
#pragma unroll
      for (int r = 0; r < 4; ++r) {
        const int row = row0 + wr + i*16 + ((lane >> 4) << 2) + r;
        const float v = acc[i][j][r] + bv;
        if (mode == 0) outb[(size_t)row * ldc + col] = (bf16_t)v;
        else           outf[(size_t)row * ldc + col] = v;
      }
    }
  }
}

// ---------------------------------------------------------------------------
// kv_part: Mpart[bh][ch][e][d] += K[n][e]*V[n][d] over n in 128-chunk.
// K/V are strided views of qkv: row n at qkv[(b*2048+n)*3072 + base_col].
// grid (32 = 16 ch x 2 dhalf, 16 bh). fp32 LDS (cvt once).
__global__ __launch_bounds__(256) void kv_part(
    const bf16_t* __restrict__ qkv, float* __restrict__ Mpart)
{
  __shared__ float Ksf[64][128];   // 32 KB
  __shared__ float Vsf[64][64];    // 16 KB
  const int t = threadIdx.x;
  const int ch = blockIdx.x >> 1, dh = blockIdx.x & 1, bh = blockIdx.y;
  const int b = bh >> 3, h = bh & 7;
  const bf16_t* Kg = qkv + (size_t)(b * 2048) * 3072 + 1024 + h * 128;
  const bf16_t* Vg = qkv + (size_t)(b * 2048) * 3072 + 2048 + h * 128 + dh * 64;
  const int e0 = (t >> 4) * 8, d0 = (t & 15) * 4;
  float acc[8][4] = {};

  for (int sub = 0; sub < 2; ++sub) {
    const int n0 = ch * 128 + sub * 64;
#pragma unroll
    for (int p = 0; p < 4; ++p) {           // K: 1024 groups of 8
      const int idx = t + p * 256;
      const int r = idx >> 4, c = (idx & 15) * 8;
      const bf16x8 k8 = *(const bf16x8*)(Kg + (size_t)(n0 + r) * 3072 + c);
      float4 f0 = { (float)k8[0], (float)k8[1], (float)k8[2], (float)k8[3] };
      float4 f1 = { (float)k8[4], (float)k8[5], (float)k8[6], (float)k8[7] };
      *(float4*)&Ksf[r][c]     = f0;
      *(float4*)&Ksf[r][c + 4] = f1;
    }
#pragma unroll
    for (int p = 0; p < 2; ++p) {           // V: 512 groups of 8
      const int idx = t + p * 256;
      const int r = idx >> 3, c = (idx & 7) * 8;
      const bf16x8 v8 = *(const bf16x8*)(Vg + (size_t)(n0 + r) * 3072 + c);
      float4 f0 = { (float)v8[0], (float)v8[1], (float)v8[2], (float)v8[3] };
      float4 f1 = { (float)v8[4], (float)v8[5], (float)v8[6], (float)v8[7] };
      *(float4*)&Vsf[r][c]     = f0;
      *(float4*)&Vsf[r][c + 4] = f1;
    }
    __syncthreads();
    for (int n = 0; n < 64; ++n) {
      const float4 ka = *(const float4*)&Ksf[n][e0];
      const float4 kb = *(const float4*)&Ksf[n][e0 + 4];
      const float4 vv = *(const float4*)&Vsf[n][d0];
      const float kf[8] = { ka.x, ka.y, ka.z, ka.w, kb.x, kb.y, kb.z, kb.w };
      const float vf[4] = { vv.x, vv.y, vv.z, vv.w };
#pragma unroll
      for (int i = 0; i < 8; ++i)
#pragma unroll
        for (int j = 0; j < 4; ++j) acc[i][j] += kf[i] * vf[j];
    }
    __syncthreads();
  }

  float* op = Mpart + ((size_t)(bh * 16 + ch) << 14) + dh * 64;
#pragma unroll
  for (int i = 0; i < 8; ++i)
    *(float4*)&op[(e0 + i) * 128 + d0] = *(const float4*)&acc[i][0];
}

// ---------------------------------------------------------------------------
// reduce_m: M[bh][e][d] (bf16, ROW-major) = sum_{ch<16} Mpart[bh][ch][e][d]
// grid (8, 16); fully coalesced fp32 reads and u16x8 writes (no transpose).
__global__ __launch_bounds__(256) void reduce_m(
    const float* __restrict__ Mpart, bf16_t* __restrict__ Mb)
{
  const int t = threadIdx.x, bh = blockIdx.y;
  const int task = blockIdx.x * 256 + t;    // 0..2047
  const int e = task >> 4, doct = task & 15;
  const float* base = Mpart + ((size_t)(bh * 16) << 14) + e * 128 + doct * 8;
  float s[8] = {};
#pragma unroll
  for (int ch = 0; ch < 16; ++ch) {
    const float* p = base + ((size_t)ch << 14);
    const float4 v0 = *(const float4*)p;
    const float4 v1 = *(const float4*)(p + 4);
    s[0] += v0.x; s[1] += v0.y; s[2] += v0.z; s[3] += v0.w;
    s[4] += v1.x; s[5] += v1.y; s[6] += v1.z; s[7] += v1.w;
  }
  u16x8 wv;
#pragma unroll
  for (int j = 0; j < 8; ++j) { bf16_t bb = (bf16_t)s[j]; wv[j] = *(u16*)&bb; }
  *(u16x8*)(Mb + (size_t)bh * 16384 + e * 128 + doct * 8) = wv;
}

// ---------------------------------------------------------------------------
// wprime: Wt_b[o][h*128+e] = sum_d wob[o][h*128+d] * M[bh][e][d].  K=128.
// A = wob rows (o, lda=1024, col base h*128); Bt = M[bh] rows (e, ldb=128).
// grid (8 o-tiles, 16 bh).
__global__ __launch_bounds__(256) void wprime_kernel(
    const bf16_t* __restrict__ wob, const bf16_t* __restrict__ Mb,
    bf16_t* __restrict__ Wt)
{
  __shared__ __align__(16) short As[128*32];
  __shared__ __align__(16) short Bs[128*32];
  const int t    = threadIdx.x;
  const int lane = t & 63;
  const int w    = t >> 6;
  const int wr   = (w >> 1) << 6;
  const int wc   = (w & 1) << 6;
  const int lrow = lane & 15;
  const int kq   = (lane >> 4) << 3;
  const int o0   = blockIdx.x * 128;
  const int bh   = blockIdx.y, b = bh >> 3, h = bh & 7;
  const bf16_t* A  = wob + (size_t)o0 * 1024 + h * 128;
  const bf16_t* Bt = Mb + (size_t)bh * 16384;

  const int i0 = t, i1 = t + 256;
  const bf16_t* a0 = A  + (size_t)(i0 >> 2) * 1024 + ((i0 & 3) << 3);
  const bf16_t* a1 = A  + (size_t)(i1 >> 2) * 1024 + ((i1 & 3) << 3);
  const bf16_t* b0 = Bt + (size_t)(i0 >> 2) * 128  + ((i0 & 3) << 3);
  const bf16_t* b1 = Bt + (size_t)(i1 >> 2) * 128  + ((i1 & 3) << 3);
  short* sa0 = &As[i0 * 8]; short* sa1 = &As[i1 * 8];
  short* sb0 = &Bs[i0 * 8]; short* sb1 = &Bs[i1 * 8];

  fx4 acc[4][4] = {};

  for (int k0 = 0; k0 < 128; k0 += 32) {
    gl_lds16(a0 + k0, sa0);
    gl_lds16(a1 + k0, sa1);
    gl_lds16(b0 + k0, sb0);
    gl_lds16(b1 + k0, sb1);
    __syncthreads();
    bf16x8 af[4], bfr[4];
#pragma unroll
    for (int i = 0; i < 4; ++i)
      af[i] = *(const bf16x8*)&As[(wr + i*16 + lrow)*32 + kq];
#pragma unroll
    for (int j = 0; j < 4; ++j)
      bfr[j] = *(const bf16x8*)&Bs[(wc + j*16 + lrow)*32 + kq];
#pragma unroll
    for (int i = 0; i < 4; ++i)
#pragma unroll
      for (int j = 0; j < 4; ++j)
        acc[i][j] = __builtin_amdgcn_mfma_f32_16x16x32_bf16(af[i], bfr[j], acc[i][j], 0, 0, 0);
    __syncthreads();
  }

  bf16_t* obase = Wt + (size_t)b * 1048576 + h * 128;
#pragma unroll
  for (int j = 0; j < 4; ++j) {
    const int col = wc + j*16 + lrow;                 // e 0..127
#pragma unroll
    for (int i = 0; i < 4; ++i) {
#pragma unroll
      for (int r = 0; r < 4; ++r) {
        const int row = o0 + wr + i*16 + ((lane >> 4) << 2) + r;   // o
        obase[(size_t)row * 1024 + col] = (bf16_t)acc[i][j][r];
      }
    }
  }
}

// ---------------------------------------------------------------------------
extern "C" void kernel_launch(void* const* d_in, const int* in_sizes, int n_in,
                              void* d_out, int out_size, void* d_ws, size_t ws_size,
                              hipStream_t stream) {
  float* out = (float*)d_out;
  dim3 blk(256);

  int ix = -1, iwq = -1, ibq = -1, iwo = -1, ibo = -1;
  if (n_in == 5) {
    for (int i = 0; i < 5; ++i) {
      switch (in_sizes[i]) {
        case 4194304: ix  = i; break;
        case 3145728: iwq = i; break;
        case 3072:    ibq = i; break;
        case 1048576: iwo = i; break;
        case 1024:    ibo = i; break;
        default: break;
      }
    }
  }
  if (ix < 0 || iwq < 0 || ibq < 0 || iwo < 0 || ibo < 0) {
    beacon_kernel<<<dim3((out_size + 255) / 256), blk, 0, stream>>>(out, 50000.0f, out_size);
    return;
  }
  const size_t NEEDED = (size_t)40 * 1048576;
  if (ws_size < NEEDED) {
    beacon_kernel<<<dim3((out_size + 255) / 256), blk, 0, stream>>>(out, 30000.0f, out_size);
    return;
  }

  char* ws = (char*)d_ws;
  bf16_t* xb     = (bf16_t*)(ws);                          // [0,8M)
  bf16_t* wqkvb  = (bf16_t*)(ws + (size_t)8  * 1048576);   // [8,14M)
  bf16_t* wob    = (bf16_t*)(ws + (size_t)14 * 1048576);   // [14,16M)
  bf16_t* qkv    = (bf16_t*)(ws + (size_t)16 * 1048576);   // [16,40M)
  bf16_t* Mb     = (bf16_t*)(ws);                          // [0,0.5M) after gemm1
  bf16_t* Wt     = (bf16_t*)(ws + (size_t)1  * 1048576);   // [1,5M)   after gemm1
  float*  bqp    = (float*)d_out;                          // [0,12K)  until gemm1 done
  float*  Mpart  = (float*)d_out;                          // [0,16M)  after gemm1

  const float* bo = (const float*)d_in[ibo];

  conv_all_kernel <<<dim3(8195),   blk, 0, stream>>>((const float*)d_in[ix],
                                                     (const float*)d_in[iwq],
                                                     (const float*)d_in[iwo],
                                                     (const float*)d_in[ibq],
                                                     xb, wqkvb, wob, bqp);
  mfma_gemm_kernel<<<dim3(24, 32), blk, 0, stream>>>(xb, 1024, wqkvb, 1024, 0,
                                                     bqp, qkv, nullptr, 3072, 0);
  kv_part         <<<dim3(32, 16), blk, 0, stream>>>(qkv, Mpart);
  reduce_m        <<<dim3(8, 16),  blk, 0, stream>>>(Mpart, Mb);
  wprime_kernel   <<<dim3(8, 16),  blk, 0, stream>>>(wob, Mb, Wt);
  mfma_gemm_kernel<<<dim3(8, 32),  blk, 0, stream>>>(qkv, 3072, Wt, 1024, 1048576,
                                                     bo, nullptr, out, 1024, 1);
}